// Round 1
// baseline (218.640 us; speedup 1.0000x reference)
//
#include <hip/hip_runtime.h>
#include <hip/hip_bf16.h>

#define NB 32
#define NN 2048
#define DD 64
#define NC 64
#define LOG2E 1.44269504088896340736f

typedef __attribute__((ext_vector_type(8))) short short8;
typedef __attribute__((ext_vector_type(4))) float f32x4;

__device__ __forceinline__ short f2bf(float x) {
  __bf16 h = (__bf16)x;
  return __builtin_bit_cast(short, h);
}

__device__ __forceinline__ float fast_exp2(float x) {
#if __has_builtin(__builtin_amdgcn_exp2f)
  return __builtin_amdgcn_exp2f(x);
#else
  return exp2f(x);
#endif
}

// Flash-style masked attention: one block = (64 Q-rows, one batch), 4 waves,
// each wave owns 16 Q-rows. K-loop over chunks of NC=64 keys.
// LDS strides: sKt/sKtT pad to 72 bf16 (144B rows, 16B-aligned, b128
// conflict-free); sP pad to 68 fp32.
__global__ __launch_bounds__(256, 4) void gat_flash(
    const float* __restrict__ x, const int* __restrict__ adj,
    float* __restrict__ out) {
  __shared__ short sKt[64 * 72];   // [n][d] bf16 K-tile (row-major)
  __shared__ short sKtT[64 * 72];  // [d][kc] bf16 V^T-tile
  __shared__ float sP[4][16 * 68]; // per-wave P round-trip (fp32)

  const int tid = threadIdx.x;
  const int w = tid >> 6;
  const int l = tid & 63;
  const int lane16 = l & 15;
  const int quad = l >> 4;
  const int qtile = blockIdx.x;
  const int b = blockIdx.y;

  // ---- Q fragments (A-layout), pre-scaled by (1/8)*log2(e) ----
  const int qrow = qtile * 64 + w * 16 + lane16;
  const float* qp = x + ((size_t)b * NN + qrow) * DD;
  const float qs = 0.125f * LOG2E;
  short8 aq[2];
#pragma unroll
  for (int ks = 0; ks < 2; ++ks) {
    const float4* p4 = (const float4*)(qp + ks * 32 + quad * 8);
    float4 v0 = p4[0], v1 = p4[1];
    short8 a;
    a[0] = f2bf(v0.x * qs); a[1] = f2bf(v0.y * qs);
    a[2] = f2bf(v0.z * qs); a[3] = f2bf(v0.w * qs);
    a[4] = f2bf(v1.x * qs); a[5] = f2bf(v1.y * qs);
    a[6] = f2bf(v1.z * qs); a[7] = f2bf(v1.w * qs);
    aq[ks] = a;
  }

  f32x4 acc[4] = {{0.f, 0.f, 0.f, 0.f},
                  {0.f, 0.f, 0.f, 0.f},
                  {0.f, 0.f, 0.f, 0.f},
                  {0.f, 0.f, 0.f, 0.f}};
  float m_run[4], l_run[4];
#pragma unroll
  for (int r = 0; r < 4; ++r) { m_run[r] = -1e12f; l_run[r] = 0.f; }

  const int qrow_base = qtile * 64 + w * 16 + quad * 4; // + r

  for (int kb = 0; kb < NN; kb += NC) {
    // adjacency for this wave's 16x64 S-tile (issued early to hide latency)
    int adjv[4][4];
#pragma unroll
    for (int nt = 0; nt < 4; ++nt)
#pragma unroll
      for (int r = 0; r < 4; ++r)
        adjv[nt][r] = adj[(size_t)(qrow_base + r) * NN + kb + nt * 16 + lane16];

    // ---- stage x[b, kb..kb+64, :] fp32 -> sKt bf16 ----
#pragma unroll
    for (int it = 0; it < 4; ++it) {
      int flat = it * 256 + tid;
      int n = flat >> 4, dg = flat & 15;
      float4 v = *(const float4*)(x + ((size_t)b * NN + kb + n) * DD + dg * 4);
      short4 s4;
      s4.x = f2bf(v.x); s4.y = f2bf(v.y); s4.z = f2bf(v.z); s4.w = f2bf(v.w);
      *(short4*)&sKt[n * 72 + dg * 4] = s4;
    }
    __syncthreads();

    // ---- transpose sKt -> sKtT (column reads broadcast; b128 writes) ----
    {
      int d = tid & 63, n0 = (tid >> 6) * 16;
      short8 t0, t1;
#pragma unroll
      for (int i = 0; i < 8; ++i) t0[i] = sKt[(n0 + i) * 72 + d];
#pragma unroll
      for (int i = 0; i < 8; ++i) t1[i] = sKt[(n0 + 8 + i) * 72 + d];
      *(short8*)&sKtT[d * 72 + n0] = t0;
      *(short8*)&sKtT[d * 72 + n0 + 8] = t1;
    }
    __syncthreads();

    // ---- S = Q K^T (already in exp2 units) ----
    f32x4 s[4] = {{0.f, 0.f, 0.f, 0.f},
                  {0.f, 0.f, 0.f, 0.f},
                  {0.f, 0.f, 0.f, 0.f},
                  {0.f, 0.f, 0.f, 0.f}};
#pragma unroll
    for (int ks = 0; ks < 2; ++ks)
#pragma unroll
      for (int nt = 0; nt < 4; ++nt) {
        short8 bk =
            *(const short8*)&sKt[(nt * 16 + lane16) * 72 + ks * 32 + quad * 8];
        s[nt] = __builtin_amdgcn_mfma_f32_16x16x32_bf16(aq[ks], bk, s[nt], 0, 0, 0);
      }

    // ---- mask + online softmax; rows = quad*4 + r ----
#pragma unroll
    for (int r = 0; r < 4; ++r) {
      float pr[4];
      float mx = -1e12f;
#pragma unroll
      for (int nt = 0; nt < 4; ++nt) {
        float sv = adjv[nt][r] > 0 ? s[nt][r] : -1e12f;
        pr[nt] = sv;
        mx = fmaxf(mx, sv);
      }
#pragma unroll
      for (int off = 8; off >= 1; off >>= 1)
        mx = fmaxf(mx, __shfl_xor(mx, off, 64));
      float mnew = fmaxf(m_run[r], mx);
      float alpha = fast_exp2(m_run[r] - mnew);
      m_run[r] = mnew;
      float sum = 0.f;
#pragma unroll
      for (int nt = 0; nt < 4; ++nt) {
        float pv = fast_exp2(pr[nt] - mnew);
        pr[nt] = pv;
        sum += pv;
      }
#pragma unroll
      for (int off = 8; off >= 1; off >>= 1)
        sum += __shfl_xor(sum, off, 64);
      l_run[r] = l_run[r] * alpha + sum;
#pragma unroll
      for (int dt = 0; dt < 4; ++dt) acc[dt][r] *= alpha;
#pragma unroll
      for (int nt = 0; nt < 4; ++nt)
        sP[w][(quad * 4 + r) * 68 + nt * 16 + lane16] = pr[nt];
    }

    // ---- O += P V (P via LDS round-trip C-layout -> A-layout) ----
#pragma unroll
    for (int ks = 0; ks < 2; ++ks) {
      const float* prow = &sP[w][lane16 * 68 + ks * 32 + quad * 8];
      float4 p0 = *(const float4*)prow;
      float4 p1 = *(const float4*)(prow + 4);
      short8 ap;
      ap[0] = f2bf(p0.x); ap[1] = f2bf(p0.y);
      ap[2] = f2bf(p0.z); ap[3] = f2bf(p0.w);
      ap[4] = f2bf(p1.x); ap[5] = f2bf(p1.y);
      ap[6] = f2bf(p1.z); ap[7] = f2bf(p1.w);
#pragma unroll
      for (int dt = 0; dt < 4; ++dt) {
        short8 bv = *(const short8*)&sKtT[(dt * 16 + lane16) * 72 + ks * 32 +
                                          quad * 8];
        acc[dt] = __builtin_amdgcn_mfma_f32_16x16x32_bf16(ap, bv, acc[dt], 0, 0, 0);
      }
    }
    __syncthreads(); // protect sKt/sKtT before next chunk's staging
  }

  // ---- epilogue: O / l ----
#pragma unroll
  for (int r = 0; r < 4; ++r) {
    float inv = 1.0f / l_run[r];
    float* orow = out + ((size_t)b * NN + qrow_base + r) * DD;
#pragma unroll
    for (int dt = 0; dt < 4; ++dt)
      orow[dt * 16 + lane16] = acc[dt][r] * inv;
  }
}

extern "C" void kernel_launch(void* const* d_in, const int* in_sizes, int n_in,
                              void* d_out, int out_size, void* d_ws,
                              size_t ws_size, hipStream_t stream) {
  const float* x = (const float*)d_in[0];
  const int* adj = (const int*)d_in[1];
  float* out = (float*)d_out;
  gat_flash<<<dim3(32, 32), 256, 0, stream>>>(x, adj, out);
}